// Round 2
// baseline (513.679 us; speedup 1.0000x reference)
//
#include <hip/hip_runtime.h>
#include <hip/hip_bf16.h>

// Problem: B=32, S=2048, ENC=1024, DEC=512
//   h_proj[b,e]   = sum_d hidden[b,d] * W[e,d]            (Wh = W[:, :512])
//   e_proj[b,s,d] = sum_e enc[b,s,e] * W[d, 512+e]        (We = W[:, 512:])
//   energy = tanh(e_proj + h_proj + bias); scores = v . energy; attn = softmax_s

typedef __attribute__((ext_vector_type(8))) short bf16x8;
typedef __attribute__((ext_vector_type(4))) float f32x4;

__device__ __forceinline__ ushort f2bf(float x) {
    __hip_bfloat16 h = __float2bfloat16(x);
    return *reinterpret_cast<ushort*>(&h);
}

__device__ __forceinline__ bf16x8 pack8(float4 a, float4 b) {
    bf16x8 o;
    o[0] = (short)f2bf(a.x); o[1] = (short)f2bf(a.y);
    o[2] = (short)f2bf(a.z); o[3] = (short)f2bf(a.w);
    o[4] = (short)f2bf(b.x); o[5] = (short)f2bf(b.y);
    o[6] = (short)f2bf(b.z); o[7] = (short)f2bf(b.w);
    return o;
}

// ws layout (bytes):
//   [0, 1MB)            : Wbf  bf16 [512][1024]  (We: row n=d, col k=e, k-contiguous)
//   [1MB, 1MB+64KB)     : hb   f32  [32][512]    (h_proj + bias)
//   [1MB+64KB, +256KB)  : scores f32 [32][2048]  (zeroed by prep; eproj atomicAdds)
#define WS_WBF   0
#define WS_HB    (1u << 20)
#define WS_SCORE ((1u << 20) + (64u << 10))

// ---- prep: convert We->bf16 (blocks 0..511), hproj (512..575), zero scores (576..639)
__global__ void prep_kernel(const float* __restrict__ W,
                            const float* __restrict__ hidden,
                            const float* __restrict__ bias,
                            ushort* __restrict__ Wbf,
                            float* __restrict__ hb,
                            float* __restrict__ score) {
    const int bid = blockIdx.x, tid = threadIdx.x;
    if (bid < 512) {
        int idx = bid * 256 + tid;
        int d  = idx >> 8;
        int e4 = (idx & 255) * 4;
        float4 f = *(const float4*)(W + (size_t)d * 1536 + 512 + e4);
        ushort4 u;
        u.x = f2bf(f.x); u.y = f2bf(f.y); u.z = f2bf(f.z); u.w = f2bf(f.w);
        *(ushort4*)(Wbf + (size_t)d * 1024 + e4) = u;
    } else if (bid < 576) {
        int idx = (bid - 512) * 256 + tid;        // 0..16383 = 32*512
        int b = idx >> 9, d = idx & 511;
        const float4* hp = (const float4*)(hidden + b * 512);
        const float4* wp = (const float4*)(W + (size_t)d * 1536);
        float acc = 0.f;
#pragma unroll 8
        for (int j = 0; j < 128; ++j) {
            float4 h = hp[j], w = wp[j];
            acc += h.x * w.x + h.y * w.y + h.z * w.z + h.w * w.w;
        }
        hb[idx] = acc + bias[d];
    } else {
        int idx = (bid - 576) * 256 + tid;        // 16384 threads x 4 floats = 65536
        float4 z = {0.f, 0.f, 0.f, 0.f};
        *(float4*)(score + (size_t)idx * 4) = z;
    }
}

// ---- main: e_proj GEMM (M=65536,N=512,K=1024) fused tanh + v-dot -> scores ----
// Grid 2048 = 1024 M-blocks x 2 N-blocks. Block 256 thr = 4 waves, wave 64x64.
// BM=64, BN=256, BK=32.
//
// Round-1 post-mortem: launch_bounds(256,4) forced VGPR=64 -> scratch spills
// (WRITE_SIZE 0.5->12.8MB); and __syncthreads' implicit vmcnt(0) drained all
// in-flight loads every group -> every pipe <22% busy. This version removes
// BOTH vmcnt drains and the spills:
//   * A is reg-staged: global f32 -> regs -> cvt once -> bf16 LDS ring (4 x
//     4KB). The f32->bf16 cvt was previously done 16x-redundantly in the
//     inner loop (per mt per wave); now once per element, and the A-frag is
//     ONE ds_read_b128 instead of two + pack8.
//   * All vmem ops are compiler-tracked register loads, so the compiler emits
//     minimal counted vmcnt(N) before each use, leaving newer loads in
//     flight. Barriers are raw s_barrier + lgkmcnt(0) (no vmcnt!): the only
//     cross-wave dep is ds_write -> ds_read.
//   * Ring discipline: at iter kt we write slot (kt+1)&3, read slot kt&3;
//     barrier skew <= 1 iter, so concurrent writer/reader slots differ by 2
//     mod 4 -> race-free. Steady state keeps A(kt+2),A(kt+3),B(kt+1)
//     outstanding across barriers.
//   * launch_bounds(256,3): ~70 VGPR + 64 acc <= 170 budget, no spills.
// LDS bank swizzle: bf16 row = 64B; slot' = slot ^ (row&3) spreads the wave's
// 64 b128 reads evenly (8 per 4-bank group = the b128 floor).
__launch_bounds__(256, 3)
__global__ void eproj_scores(const float* __restrict__ enc,
                             const ushort* __restrict__ Wbf,
                             const float* __restrict__ hb,
                             const float* __restrict__ v,
                             float* __restrict__ scores) {
    __shared__ alignas(16) ushort Abuf[4][2048];   // 4-deep ring of [64][32] bf16, 16KB

    const int tid  = threadIdx.x;
    const int lane = tid & 63, w = tid >> 6;
    const int q = lane >> 4, ln = lane & 15;
    // XCD-aware bijective remap: paired N-blocks of one M-tile land on one XCD
    const int  swz  = (blockIdx.x & 7) * 256 + (blockIdx.x >> 3);
    const int  nblk = swz & 1;
    const long m0   = (long)(swz >> 1) * 64;
    const int  bidx = (int)(m0 >> 11);        // 32 M-blocks per batch row, no straddle
    const int  n0   = nblk * 256 + w * 64;    // wave's 64-col slice

    f32x4 acc[4][4];
#pragma unroll
    for (int mt = 0; mt < 4; ++mt)
#pragma unroll
        for (int nt = 0; nt < 4; ++nt)
            acc[mt][nt] = (f32x4){0.f, 0.f, 0.f, 0.f};

    // B row pointers (per nt); k advances 32 bf16 per kt (imm-foldable offsets)
    const ushort* bptr[4];
#pragma unroll
    for (int nt = 0; nt < 4; ++nt)
        bptr[nt] = Wbf + (size_t)(n0 + nt * 16 + ln) * 1024 + q * 8;

    // A staging: thread t owns row sr = t>>2, logical k-slot sq = t&3
    // (8 floats = 32B global -> one 16B bf16 slot). Swizzled slot = sq^(sr&3).
    const int sr = tid >> 2, sq = tid & 3;
    const float* aptr = enc + (m0 + sr) * 1024 + sq * 8;   // +kt*32 floats per kt
    const int awoff = sr * 32 + ((sq ^ (sr & 3)) << 3);    // ushort index

    // A-frag read offsets per mt: row rA, logical slot q, swizzled q^(rA&3)
    int rdoff[4];
#pragma unroll
    for (int mt = 0; mt < 4; ++mt) {
        int rA = mt * 16 + ln;
        rdoff[mt] = rA * 32 + ((q ^ (rA & 3)) << 3);
    }

    // ---- prologue: A(0),A(1) regs; B(0) frags; write A(0); reload A(2) ----
    float4 ar[2][2];
    ar[0][0] = *(const float4*)(aptr);
    ar[0][1] = *(const float4*)(aptr + 4);
    ar[1][0] = *(const float4*)(aptr + 32);
    ar[1][1] = *(const float4*)(aptr + 36);

    bf16x8 bfr[2][4];
#pragma unroll
    for (int nt = 0; nt < 4; ++nt)
        bfr[0][nt] = *(const bf16x8*)(bptr[nt]);

    *(bf16x8*)(&Abuf[0][awoff]) = pack8(ar[0][0], ar[0][1]);   // A(0) -> slot 0
    ar[0][0] = *(const float4*)(aptr + 64);                    // A(2)
    ar[0][1] = *(const float4*)(aptr + 68);

    // ---- main loop: 32 kt, one raw barrier each, zero vmcnt drains ----
    for (int g = 0; g < 8; ++g) {
#pragma unroll
        for (int j = 0; j < 4; ++j) {
            const int kt = g * 4 + j;
            const int p  = (j + 1) & 1;           // reg set holding A(kt+1)
            if (kt + 1 < 32) {
                // cvt+write A(kt+1) -> slot (kt+1)&3 (compiler waits only its regs)
                *(bf16x8*)(&Abuf[(j + 1) & 3][awoff]) = pack8(ar[p][0], ar[p][1]);
                if (kt + 3 < 32) {                // reload freed set with A(kt+3)
                    ar[p][0] = *(const float4*)(aptr + (kt + 3) * 32);
                    ar[p][1] = *(const float4*)(aptr + (kt + 3) * 32 + 4);
                }
                asm volatile("s_waitcnt lgkmcnt(0)" ::: "memory");  // ds_write visible
            }
            __builtin_amdgcn_s_barrier();         // NO vmcnt drain
            asm volatile("" ::: "memory");

            if (kt + 1 < 32) {                    // B prefetch for kt+1 (L2-hot)
#pragma unroll
                for (int nt = 0; nt < 4; ++nt)
                    bfr[p][nt] = *(const bf16x8*)(bptr[nt] + (size_t)(kt + 1) * 32);
            }
#pragma unroll
            for (int mt = 0; mt < 4; ++mt) {
                bf16x8 af = *(const bf16x8*)(&Abuf[j][rdoff[mt]]);
#pragma unroll
                for (int nt = 0; nt < 4; ++nt)
                    acc[mt][nt] = __builtin_amdgcn_mfma_f32_16x16x32_bf16(
                        af, bfr[j & 1][nt], acc[mt][nt], 0, 0, 0);
            }
        }
    }

    // epilogue: energy = tanh(acc + hb), partial = sum_d v[d]*energy (N-slice)
    float partial[4][4];
#pragma unroll
    for (int mt = 0; mt < 4; ++mt)
#pragma unroll
        for (int r = 0; r < 4; ++r) partial[mt][r] = 0.f;

#pragma unroll
    for (int nt = 0; nt < 4; ++nt) {
        int d = n0 + nt * 16 + ln;
        float hbv = hb[bidx * 512 + d];
        float vv  = v[d];
#pragma unroll
        for (int mt = 0; mt < 4; ++mt)
#pragma unroll
            for (int r = 0; r < 4; ++r) {
                float x = acc[mt][nt][r] + hbv;
                float e = __expf(2.f * x);          // tanh(x) = 1 - 2/(e^{2x}+1)
                partial[mt][r] += vv * (1.f - 2.f / (e + 1.f));
            }
    }
#pragma unroll
    for (int mt = 0; mt < 4; ++mt)
#pragma unroll
        for (int r = 0; r < 4; ++r) {
            float s = partial[mt][r];
            s += __shfl_xor(s, 1);
            s += __shfl_xor(s, 2);
            s += __shfl_xor(s, 4);
            s += __shfl_xor(s, 8);
            partial[mt][r] = s;
        }

    __syncthreads();                     // all LDS reads done; reuse Abuf for spart
    float* spart = (float*)Abuf;         // [4][64]
    if (ln == 0) {
#pragma unroll
        for (int mt = 0; mt < 4; ++mt)
#pragma unroll
            for (int r = 0; r < 4; ++r)
                spart[w * 64 + mt * 16 + q * 4 + r] = partial[mt][r];
    }
    __syncthreads();
    if (tid < 64)
        atomicAdd(&scores[m0 + tid],
                  spart[tid] + spart[64 + tid] + spart[128 + tid] + spart[192 + tid]);
}

// ---- softmax over S=2048 per b ----
__global__ void softmax_kernel(const float* __restrict__ scores, float* __restrict__ out) {
    int b = blockIdx.x;
    const float* sc = scores + b * 2048;
    __shared__ float wred[4], wsum[4];

    float lmax = -1e30f;
    for (int i = threadIdx.x; i < 2048; i += 256) lmax = fmaxf(lmax, sc[i]);
#pragma unroll
    for (int m = 1; m < 64; m <<= 1) lmax = fmaxf(lmax, __shfl_xor(lmax, m));
    if ((threadIdx.x & 63) == 0) wred[threadIdx.x >> 6] = lmax;
    __syncthreads();
    float gmax = fmaxf(fmaxf(wred[0], wred[1]), fmaxf(wred[2], wred[3]));

    float lsum = 0.f;
    for (int i = threadIdx.x; i < 2048; i += 256) lsum += __expf(sc[i] - gmax);
#pragma unroll
    for (int m = 1; m < 64; m <<= 1) lsum += __shfl_xor(lsum, m);
    if ((threadIdx.x & 63) == 0) wsum[threadIdx.x >> 6] = lsum;
    __syncthreads();
    float inv = 1.f / (wsum[0] + wsum[1] + wsum[2] + wsum[3]);

    for (int i = threadIdx.x; i < 2048; i += 256)
        out[b * 2048 + i] = __expf(sc[i] - gmax) * inv;
}

extern "C" void kernel_launch(void* const* d_in, const int* in_sizes, int n_in,
                              void* d_out, int out_size, void* d_ws, size_t ws_size,
                              hipStream_t stream) {
    const float* hidden = (const float*)d_in[0];   // 32 x 512
    const float* enc    = (const float*)d_in[1];   // 32 x 2048 x 1024
    const float* W      = (const float*)d_in[2];   // 512 x 1536
    const float* bias   = (const float*)d_in[3];   // 512
    const float* v      = (const float*)d_in[4];   // 512
    float* out = (float*)d_out;                    // 32 x 1 x 2048

    char* ws = (char*)d_ws;
    ushort* Wbf   = (ushort*)(ws + WS_WBF);
    float*  hb    = (float*)(ws + WS_HB);
    float*  score = (float*)(ws + WS_SCORE);

    hipLaunchKernelGGL(prep_kernel,  dim3(640),  dim3(256), 0, stream,
                       W, hidden, bias, Wbf, hb, score);
    hipLaunchKernelGGL(eproj_scores, dim3(2048), dim3(256), 0, stream,
                       enc, Wbf, hb, v, score);
    hipLaunchKernelGGL(softmax_kernel, dim3(32), dim3(256), 0, stream, score, out);
}

// Round 4
// 513.481 us; speedup vs baseline: 1.0004x; 1.0004x over previous
//
#include <hip/hip_runtime.h>
#include <hip/hip_bf16.h>

// Problem: B=32, S=2048, ENC=1024, DEC=512
//   h_proj[b,e]   = sum_d hidden[b,d] * W[e,d]            (Wh = W[:, :512])
//   e_proj[b,s,d] = sum_e enc[b,s,e] * W[d, 512+e]        (We = W[:, 512:])
//   energy = tanh(e_proj + h_proj + bias); scores = v . energy; attn = softmax_s

typedef __attribute__((ext_vector_type(8))) short bf16x8;
typedef __attribute__((ext_vector_type(4))) float f32x4;

__device__ __forceinline__ ushort f2bf(float x) {
    __hip_bfloat16 h = __float2bfloat16(x);
    return *reinterpret_cast<ushort*>(&h);
}

__device__ __forceinline__ ushort4 pack4(float4 a) {
    ushort4 o;
    o.x = f2bf(a.x); o.y = f2bf(a.y); o.z = f2bf(a.z); o.w = f2bf(a.w);
    return o;
}

// ws layout (bytes):
//   [0, 1MB)            : Wbf  bf16 [512][1024]  (We: row n=d, col k=e, k-contiguous)
//   [1MB, 1MB+64KB)     : hb   f32  [32][512]    (h_proj + bias)
//   [1MB+64KB, +256KB)  : scores f32 [32][2048]  (written directly by eproj)
#define WS_WBF   0
#define WS_HB    (1u << 20)
#define WS_SCORE ((1u << 20) + (64u << 10))

// ---- prep: convert We->bf16 (blocks 0..511), hproj (blocks 512..575) ----
__global__ void prep_kernel(const float* __restrict__ W,
                            const float* __restrict__ hidden,
                            const float* __restrict__ bias,
                            ushort* __restrict__ Wbf,
                            float* __restrict__ hb) {
    const int bid = blockIdx.x, tid = threadIdx.x;
    if (bid < 512) {
        int idx = bid * 256 + tid;
        int d  = idx >> 8;
        int e4 = (idx & 255) * 4;
        float4 f = *(const float4*)(W + (size_t)d * 1536 + 512 + e4);
        ushort4 u;
        u.x = f2bf(f.x); u.y = f2bf(f.y); u.z = f2bf(f.z); u.w = f2bf(f.w);
        *(ushort4*)(Wbf + (size_t)d * 1024 + e4) = u;
    } else {
        int idx = (bid - 512) * 256 + tid;        // 0..16383 = 32*512
        int b = idx >> 9, d = idx & 511;
        const float4* hp = (const float4*)(hidden + b * 512);
        const float4* wp = (const float4*)(W + (size_t)d * 1536);
        float acc = 0.f;
#pragma unroll 8
        for (int j = 0; j < 128; ++j) {
            float4 h = hp[j], w = wp[j];
            acc += h.x * w.x + h.y * w.y + h.z * w.z + h.w * w.w;
        }
        hb[idx] = acc + bias[d];
    }
}

// ---- main: e_proj GEMM (M=65536,N=512,K=1024) fused tanh + v-dot -> scores ----
// Round-2 post-mortem: three different pipeline structures all ~205-220us with
// every pipe <22% busy. Invariant limiter = the A (enc) stream: BN=256 read
// enc TWICE (512MB demanded); measured effective A-rate 512MB/221us = 2.3TB/s
// = ~9.5 B/cyc/CU = the per-CU HBM-share ceiling (m13). The vmcnt pacing on
// the A-reload meters the whole loop.
//
// Fix: BN=512 -> enc read ONCE (256MB). Grid 1024 M-blocks, 512 thr = 8
// waves, each wave the SAME verified 64x64 tile (n0 = w*64). Keeps the
// round-2 counted-wait ring (zero vmcnt drains in the loop):
//   * A reg-staged: each thread one float4/kt -> cvt once -> 8B LDS write
//     into a 4-deep ring of [64][32]bf16 slots (16KB). 16B-chunk XOR swizzle
//     (chunk = (sq>>1)^(sr&3)) matches the read-side rdoff swizzle.
//   * Barriers are raw s_barrier + lgkmcnt(0) only; all global loads are
//     compiler-tracked counted vmcnt. In-flight A/CU = 512thr x 32B = 16KB,
//     enough to sustain full per-CU HBM share at ~900cy latency.
//   * Ring safety: write slot (kt+1)&3, read slot kt&3; s_barrier bounds
//     skew to 1 iter -> writer/reader slots always differ by >=2 mod 4.
//   * BN=512 covers all d in-block: scores written DIRECTLY (no atomics,
//     no zeroing kernel).
// (Round-3 bench was an infra failure — container failed twice, no counters.
//  Barrier-uniformity / ring-race / VGPR audit passed; resubmitting.)
__launch_bounds__(512, 2)
__global__ void eproj_scores(const float* __restrict__ enc,
                             const ushort* __restrict__ Wbf,
                             const float* __restrict__ hb,
                             const float* __restrict__ v,
                             float* __restrict__ scores) {
    __shared__ alignas(16) ushort Abuf[4][2048];   // 4-deep ring of [64][32] bf16, 16KB

    const int tid  = threadIdx.x;
    const int lane = tid & 63, w = tid >> 6;       // 8 waves
    const int q = lane >> 4, ln = lane & 15;
    const long m0   = (long)blockIdx.x * 64;
    const int  bidx = (int)(m0 >> 11);             // 32 M-blocks per batch row
    const int  n0   = w * 64;                      // wave's 64-col slice of N=512

    f32x4 acc[4][4];
#pragma unroll
    for (int mt = 0; mt < 4; ++mt)
#pragma unroll
        for (int nt = 0; nt < 4; ++nt)
            acc[mt][nt] = (f32x4){0.f, 0.f, 0.f, 0.f};

    // B row pointers (per nt); k advances 32 bf16 per kt
    const ushort* bptr[4];
#pragma unroll
    for (int nt = 0; nt < 4; ++nt)
        bptr[nt] = Wbf + (size_t)(n0 + nt * 16 + ln) * 1024 + q * 8;

    // A staging: thread owns row sr = tid>>3 (0..63), 4-float slot sq = tid&7.
    // Global: one float4 per kt. LDS: 8B ushort4 at 16B-chunk-swizzled offset.
    const int sr = tid >> 3, sq = tid & 7;
    const float* aptr = enc + (m0 + sr) * 1024 + sq * 4;   // +kt*32 floats per kt
    const int awoff = sr * 32 + (((sq >> 1) ^ (sr & 3)) << 3) + (sq & 1) * 4;

    // A-frag read offsets per mt: row rA, logical 16B chunk q, swizzled q^(rA&3)
    int rdoff[4];
#pragma unroll
    for (int mt = 0; mt < 4; ++mt) {
        int rA = mt * 16 + ln;
        rdoff[mt] = rA * 32 + ((q ^ (rA & 3)) << 3);
    }

    // ---- prologue: A(0),A(1) regs; B(0) frags; write A(0); reload A(2) ----
    float4 ar[2];
    ar[0] = *(const float4*)(aptr);
    ar[1] = *(const float4*)(aptr + 32);

    bf16x8 bfr[2][4];
#pragma unroll
    for (int nt = 0; nt < 4; ++nt)
        bfr[0][nt] = *(const bf16x8*)(bptr[nt]);

    *(ushort4*)(&Abuf[0][awoff]) = pack4(ar[0]);   // A(0) -> slot 0
    ar[0] = *(const float4*)(aptr + 64);           // A(2)

    // ---- main loop: 32 kt, one raw barrier each, zero vmcnt drains ----
    for (int g = 0; g < 8; ++g) {
#pragma unroll
        for (int j = 0; j < 4; ++j) {
            const int kt = g * 4 + j;
            const int p  = (j + 1) & 1;           // reg set holding A(kt+1)
            if (kt + 1 < 32) {
                // cvt+write A(kt+1) -> slot (kt+1)&3 (counted vmcnt on ar[p])
                *(ushort4*)(&Abuf[(j + 1) & 3][awoff]) = pack4(ar[p]);
                if (kt + 3 < 32)                  // reload freed set with A(kt+3)
                    ar[p] = *(const float4*)(aptr + (kt + 3) * 32);
                asm volatile("s_waitcnt lgkmcnt(0)" ::: "memory");  // ds_write visible
            }
            __builtin_amdgcn_s_barrier();         // NO vmcnt drain
            asm volatile("" ::: "memory");

            if (kt + 1 < 32) {                    // B prefetch for kt+1 (L2-hot)
#pragma unroll
                for (int nt = 0; nt < 4; ++nt)
                    bfr[p][nt] = *(const bf16x8*)(bptr[nt] + (size_t)(kt + 1) * 32);
            }
#pragma unroll
            for (int mt = 0; mt < 4; ++mt) {
                bf16x8 af = *(const bf16x8*)(&Abuf[j][rdoff[mt]]);
#pragma unroll
                for (int nt = 0; nt < 4; ++nt)
                    acc[mt][nt] = __builtin_amdgcn_mfma_f32_16x16x32_bf16(
                        af, bfr[j & 1][nt], acc[mt][nt], 0, 0, 0);
            }
        }
    }

    // epilogue: energy = tanh(acc + hb), partial = sum_d v[d]*energy (wave slice)
    float partial[4][4];
#pragma unroll
    for (int mt = 0; mt < 4; ++mt)
#pragma unroll
        for (int r = 0; r < 4; ++r) partial[mt][r] = 0.f;

#pragma unroll
    for (int nt = 0; nt < 4; ++nt) {
        int d = n0 + nt * 16 + ln;
        float hbv = hb[bidx * 512 + d];
        float vv  = v[d];
#pragma unroll
        for (int mt = 0; mt < 4; ++mt)
#pragma unroll
            for (int r = 0; r < 4; ++r) {
                float x = acc[mt][nt][r] + hbv;
                float e = __expf(2.f * x);          // tanh(x) = 1 - 2/(e^{2x}+1)
                partial[mt][r] += vv * (1.f - 2.f / (e + 1.f));
            }
    }
#pragma unroll
    for (int mt = 0; mt < 4; ++mt)
#pragma unroll
        for (int r = 0; r < 4; ++r) {
            float s = partial[mt][r];
            s += __shfl_xor(s, 1);
            s += __shfl_xor(s, 2);
            s += __shfl_xor(s, 4);
            s += __shfl_xor(s, 8);
            partial[mt][r] = s;
        }

    __syncthreads();                     // all LDS reads done; reuse Abuf for spart
    float* spart = (float*)Abuf;         // [8][64]
    if (ln == 0) {
#pragma unroll
        for (int mt = 0; mt < 4; ++mt)
#pragma unroll
            for (int r = 0; r < 4; ++r)
                spart[w * 64 + mt * 16 + q * 4 + r] = partial[mt][r];
    }
    __syncthreads();
    if (tid < 64) {
        float s = 0.f;
#pragma unroll
        for (int ww = 0; ww < 8; ++ww) s += spart[ww * 64 + tid];
        scores[m0 + tid] = s;            // direct store: block covers all d
    }
}

// ---- softmax over S=2048 per b ----
__global__ void softmax_kernel(const float* __restrict__ scores, float* __restrict__ out) {
    int b = blockIdx.x;
    const float* sc = scores + b * 2048;
    __shared__ float wred[4], wsum[4];

    float lmax = -1e30f;
    for (int i = threadIdx.x; i < 2048; i += 256) lmax = fmaxf(lmax, sc[i]);
#pragma unroll
    for (int m = 1; m < 64; m <<= 1) lmax = fmaxf(lmax, __shfl_xor(lmax, m));
    if ((threadIdx.x & 63) == 0) wred[threadIdx.x >> 6] = lmax;
    __syncthreads();
    float gmax = fmaxf(fmaxf(wred[0], wred[1]), fmaxf(wred[2], wred[3]));

    float lsum = 0.f;
    for (int i = threadIdx.x; i < 2048; i += 256) lsum += __expf(sc[i] - gmax);
#pragma unroll
    for (int m = 1; m < 64; m <<= 1) lsum += __shfl_xor(lsum, m);
    if ((threadIdx.x & 63) == 0) wsum[threadIdx.x >> 6] = lsum;
    __syncthreads();
    float inv = 1.f / (wsum[0] + wsum[1] + wsum[2] + wsum[3]);

    for (int i = threadIdx.x; i < 2048; i += 256)
        out[b * 2048 + i] = __expf(sc[i] - gmax) * inv;
}

extern "C" void kernel_launch(void* const* d_in, const int* in_sizes, int n_in,
                              void* d_out, int out_size, void* d_ws, size_t ws_size,
                              hipStream_t stream) {
    const float* hidden = (const float*)d_in[0];   // 32 x 512
    const float* enc    = (const float*)d_in[1];   // 32 x 2048 x 1024
    const float* W      = (const float*)d_in[2];   // 512 x 1536
    const float* bias   = (const float*)d_in[3];   // 512
    const float* v      = (const float*)d_in[4];   // 512
    float* out = (float*)d_out;                    // 32 x 1 x 2048

    char* ws = (char*)d_ws;
    ushort* Wbf   = (ushort*)(ws + WS_WBF);
    float*  hb    = (float*)(ws + WS_HB);
    float*  score = (float*)(ws + WS_SCORE);

    hipLaunchKernelGGL(prep_kernel,  dim3(576),  dim3(256), 0, stream,
                       W, hidden, bias, Wbf, hb);
    hipLaunchKernelGGL(eproj_scores, dim3(1024), dim3(512), 0, stream,
                       enc, Wbf, hb, v, score);
    hipLaunchKernelGGL(softmax_kernel, dim3(32), dim3(256), 0, stream, score, out);
}

// Round 5
// 512.586 us; speedup vs baseline: 1.0021x; 1.0017x over previous
//
#include <hip/hip_runtime.h>
#include <hip/hip_bf16.h>

// Problem: B=32, S=2048, ENC=1024, DEC=512
//   h_proj[b,e]   = sum_d hidden[b,d] * W[e,d]            (Wh = W[:, :512])
//   e_proj[b,s,d] = sum_e enc[b,s,e] * W[d, 512+e]        (We = W[:, 512:])
//   energy = tanh(e_proj + h_proj + bias); scores = v . energy; attn = softmax_s

typedef __attribute__((ext_vector_type(8))) short bf16x8;
typedef __attribute__((ext_vector_type(4))) float f32x4;

__device__ __forceinline__ ushort f2bf(float x) {
    __hip_bfloat16 h = __float2bfloat16(x);
    return *reinterpret_cast<ushort*>(&h);
}

__device__ __forceinline__ ushort4 pack4(float4 a) {
    ushort4 o;
    o.x = f2bf(a.x); o.y = f2bf(a.y); o.z = f2bf(a.z); o.w = f2bf(a.w);
    return o;
}

// ws layout (bytes):
//   [0, 1MB)            : Wbf  bf16 [512][1024]  (We: row n=d, col k=e, k-contiguous)
//   [1MB, 1MB+64KB)     : hb   f32  [32][512]    (h_proj + bias)
//   [1MB+64KB, +256KB)  : scores f32 [32][2048]  (written directly by eproj)
#define WS_WBF   0
#define WS_HB    (1u << 20)
#define WS_SCORE ((1u << 20) + (64u << 10))

// ---- prep: convert We->bf16 (blocks 0..511), hproj (blocks 512..575) ----
__global__ void prep_kernel(const float* __restrict__ W,
                            const float* __restrict__ hidden,
                            const float* __restrict__ bias,
                            ushort* __restrict__ Wbf,
                            float* __restrict__ hb) {
    const int bid = blockIdx.x, tid = threadIdx.x;
    if (bid < 512) {
        int idx = bid * 256 + tid;
        int d  = idx >> 8;
        int e4 = (idx & 255) * 4;
        float4 f = *(const float4*)(W + (size_t)d * 1536 + 512 + e4);
        ushort4 u;
        u.x = f2bf(f.x); u.y = f2bf(f.y); u.z = f2bf(f.z); u.w = f2bf(f.w);
        *(ushort4*)(Wbf + (size_t)d * 1024 + e4) = u;
    } else {
        int idx = (bid - 512) * 256 + tid;        // 0..16383 = 32*512
        int b = idx >> 9, d = idx & 511;
        const float4* hp = (const float4*)(hidden + b * 512);
        const float4* wp = (const float4*)(W + (size_t)d * 1536);
        float acc = 0.f;
#pragma unroll 8
        for (int j = 0; j < 128; ++j) {
            float4 h = hp[j], w = wp[j];
            acc += h.x * w.x + h.y * w.y + h.z * w.z + h.w * w.w;
        }
        hb[idx] = acc + bias[d];
    }
}

// ---- main: e_proj GEMM (M=65536,N=512,K=1024) fused tanh + v-dot -> scores ----
// Round-4 post-mortem: BN=512 halved A-demand -> dur UNCHANGED (224us, all
// pipes <13%). Per-CU math: ~2100-4200 cy per kt-step vs ~300-400 cy of work.
// Root cause: vmcnt is an IN-ORDER counter. The queue interleaved A-loads
// (HBM, ~900-2000cy) with B-loads (L2, ~300cy); each iteration's MFMA waits
// on B(kt) via vmcnt(N), which transitively forces the A-load issued 1-2
// iters earlier to have RETURNED FROM HBM. Every kt paid ~1 HBM latency.
//
// Fix (this version): decouple the two streams by slack-deepening:
//   * B-prefetch issued FIRST each iteration -> same-iter A is NEWER than
//     any B being waited on; B-waits never force same-iter A.
//   * B ring depth 4 (bfr[4][4]): B(kt+2) issued 2 iters ahead of use.
//   * A ring depth 4 (ar[4]): A(kt+5) issued at iter kt, ds_written at
//     iter kt+4 (4-iter slack); oldest A forced by a B-wait has 3-iter
//     slack (~1200+cy) instead of 1.
//   All ring indices are compile-time (&3 under the x4 unroll) -> registers,
//   not scratch. ~180 unified regs fits 2 waves/SIMD (256 cap), no spill.
// Ring safety: writer at iter kt writes LDS slot (kt+1)&3 before barrier kt;
// slowest reader is in iter kt-1 reading slot (kt-1)&3 -> differ by 2 mod 4.
// Steady-state iter time ~= max(work ~350cy, HBM_lat/3) -- latency-decoupled.
__launch_bounds__(512, 2)
__global__ void eproj_scores(const float* __restrict__ enc,
                             const ushort* __restrict__ Wbf,
                             const float* __restrict__ hb,
                             const float* __restrict__ v,
                             float* __restrict__ scores) {
    __shared__ alignas(16) ushort Abuf[4][2048];   // 4-deep ring of [64][32] bf16, 16KB

    const int tid  = threadIdx.x;
    const int lane = tid & 63, w = tid >> 6;       // 8 waves
    const int q = lane >> 4, ln = lane & 15;
    const long m0   = (long)blockIdx.x * 64;
    const int  bidx = (int)(m0 >> 11);             // 32 M-blocks per batch row
    const int  n0   = w * 64;                      // wave's 64-col slice of N=512

    f32x4 acc[4][4];
#pragma unroll
    for (int mt = 0; mt < 4; ++mt)
#pragma unroll
        for (int nt = 0; nt < 4; ++nt)
            acc[mt][nt] = (f32x4){0.f, 0.f, 0.f, 0.f};

    // B row pointers (per nt); k advances 32 bf16 per kt
    const ushort* bptr[4];
#pragma unroll
    for (int nt = 0; nt < 4; ++nt)
        bptr[nt] = Wbf + (size_t)(n0 + nt * 16 + ln) * 1024 + q * 8;

    // A staging: thread owns row sr = tid>>3 (0..63), 4-float slot sq = tid&7.
    // Global: one float4 per kt. LDS: 8B ushort4 at 16B-chunk-swizzled offset.
    const int sr = tid >> 3, sq = tid & 7;
    const float* aptr = enc + (m0 + sr) * 1024 + sq * 4;   // +kt*32 floats per kt
    const int awoff = sr * 32 + (((sq >> 1) ^ (sr & 3)) << 3) + (sq & 1) * 4;

    // A-frag read offsets per mt: row rA, logical 16B chunk q, swizzled q^(rA&3)
    int rdoff[4];
#pragma unroll
    for (int mt = 0; mt < 4; ++mt) {
        int rA = mt * 16 + ln;
        rdoff[mt] = rA * 32 + ((q ^ (rA & 3)) << 3);
    }

    // ---- prologue: A(0..3) -> ar[0..3]; B(0),B(1) -> bfr[0],bfr[1];
    //      write A(0) to slot 0; reload ar[0] = A(4) ----
    float4 ar[4];
#pragma unroll
    for (int d = 0; d < 4; ++d)
        ar[d] = *(const float4*)(aptr + d * 32);

    bf16x8 bfr[4][4];
#pragma unroll
    for (int nt = 0; nt < 4; ++nt) {
        bfr[0][nt] = *(const bf16x8*)(bptr[nt]);
        bfr[1][nt] = *(const bf16x8*)(bptr[nt] + 32);
    }

    *(ushort4*)(&Abuf[0][awoff]) = pack4(ar[0]);   // A(0) -> slot 0
    ar[0] = *(const float4*)(aptr + 4 * 32);       // A(4) (ds_written at iter 3)
    asm volatile("s_waitcnt lgkmcnt(0)" ::: "memory");

    // ---- main loop: 32 kt, one raw barrier each, zero vmcnt drains ----
    for (int g = 0; g < 8; ++g) {
#pragma unroll
        for (int j = 0; j < 4; ++j) {
            const int kt = g * 4 + j;

            // 1) B-prefetch FIRST: B(kt+2) -> bfr[(j+2)&3] (2-iter slack;
            //    keeps same-iter A-load NEWER than any waited-on B batch)
            if (kt + 2 < 32) {
#pragma unroll
                for (int nt = 0; nt < 4; ++nt)
                    bfr[(j + 2) & 3][nt] =
                        *(const bf16x8*)(bptr[nt] + (size_t)(kt + 2) * 32);
            }

            // 2) A stage: cvt+write A(kt+1) (loaded 4 iters ago), reload slot
            //    with A(kt+5) (ds_written at iter kt+4 -> 4-iter slack)
            if (kt + 1 < 32) {
                *(ushort4*)(&Abuf[(j + 1) & 3][awoff]) = pack4(ar[(j + 1) & 3]);
                if (kt + 5 < 32)
                    ar[(j + 1) & 3] = *(const float4*)(aptr + (kt + 5) * 32);
                asm volatile("s_waitcnt lgkmcnt(0)" ::: "memory");  // ds_write visible
            }
            __builtin_amdgcn_s_barrier();         // NO vmcnt drain
            asm volatile("" ::: "memory");

            // 3) MFMA on slot kt&3 == j&3 with B(kt) in bfr[j&3]
#pragma unroll
            for (int mt = 0; mt < 4; ++mt) {
                bf16x8 af = *(const bf16x8*)(&Abuf[j & 3][rdoff[mt]]);
#pragma unroll
                for (int nt = 0; nt < 4; ++nt)
                    acc[mt][nt] = __builtin_amdgcn_mfma_f32_16x16x32_bf16(
                        af, bfr[j & 3][nt], acc[mt][nt], 0, 0, 0);
            }
        }
    }

    // epilogue: energy = tanh(acc + hb), partial = sum_d v[d]*energy (wave slice)
    float partial[4][4];
#pragma unroll
    for (int mt = 0; mt < 4; ++mt)
#pragma unroll
        for (int r = 0; r < 4; ++r) partial[mt][r] = 0.f;

#pragma unroll
    for (int nt = 0; nt < 4; ++nt) {
        int d = n0 + nt * 16 + ln;
        float hbv = hb[bidx * 512 + d];
        float vv  = v[d];
#pragma unroll
        for (int mt = 0; mt < 4; ++mt)
#pragma unroll
            for (int r = 0; r < 4; ++r) {
                float x = acc[mt][nt][r] + hbv;
                float e = __expf(2.f * x);          // tanh(x) = 1 - 2/(e^{2x}+1)
                partial[mt][r] += vv * (1.f - 2.f / (e + 1.f));
            }
    }
#pragma unroll
    for (int mt = 0; mt < 4; ++mt)
#pragma unroll
        for (int r = 0; r < 4; ++r) {
            float s = partial[mt][r];
            s += __shfl_xor(s, 1);
            s += __shfl_xor(s, 2);
            s += __shfl_xor(s, 4);
            s += __shfl_xor(s, 8);
            partial[mt][r] = s;
        }

    __syncthreads();                     // all LDS reads done; reuse Abuf for spart
    float* spart = (float*)Abuf;         // [8][64]
    if (ln == 0) {
#pragma unroll
        for (int mt = 0; mt < 4; ++mt)
#pragma unroll
            for (int r = 0; r < 4; ++r)
                spart[w * 64 + mt * 16 + q * 4 + r] = partial[mt][r];
    }
    __syncthreads();
    if (tid < 64) {
        float s = 0.f;
#pragma unroll
        for (int ww = 0; ww < 8; ++ww) s += spart[ww * 64 + tid];
        scores[m0 + tid] = s;            // direct store: block covers all d
    }
}

// ---- softmax over S=2048 per b ----
__global__ void softmax_kernel(const float* __restrict__ scores, float* __restrict__ out) {
    int b = blockIdx.x;
    const float* sc = scores + b * 2048;
    __shared__ float wred[4], wsum[4];

    float lmax = -1e30f;
    for (int i = threadIdx.x; i < 2048; i += 256) lmax = fmaxf(lmax, sc[i]);
#pragma unroll
    for (int m = 1; m < 64; m <<= 1) lmax = fmaxf(lmax, __shfl_xor(lmax, m));
    if ((threadIdx.x & 63) == 0) wred[threadIdx.x >> 6] = lmax;
    __syncthreads();
    float gmax = fmaxf(fmaxf(wred[0], wred[1]), fmaxf(wred[2], wred[3]));

    float lsum = 0.f;
    for (int i = threadIdx.x; i < 2048; i += 256) lsum += __expf(sc[i] - gmax);
#pragma unroll
    for (int m = 1; m < 64; m <<= 1) lsum += __shfl_xor(lsum, m);
    if ((threadIdx.x & 63) == 0) wsum[threadIdx.x >> 6] = lsum;
    __syncthreads();
    float inv = 1.f / (wsum[0] + wsum[1] + wsum[2] + wsum[3]);

    for (int i = threadIdx.x; i < 2048; i += 256)
        out[b * 2048 + i] = __expf(sc[i] - gmax) * inv;
}

extern "C" void kernel_launch(void* const* d_in, const int* in_sizes, int n_in,
                              void* d_out, int out_size, void* d_ws, size_t ws_size,
                              hipStream_t stream) {
    const float* hidden = (const float*)d_in[0];   // 32 x 512
    const float* enc    = (const float*)d_in[1];   // 32 x 2048 x 1024
    const float* W      = (const float*)d_in[2];   // 512 x 1536
    const float* bias   = (const float*)d_in[3];   // 512
    const float* v      = (const float*)d_in[4];   // 512
    float* out = (float*)d_out;                    // 32 x 1 x 2048

    char* ws = (char*)d_ws;
    ushort* Wbf   = (ushort*)(ws + WS_WBF);
    float*  hb    = (float*)(ws + WS_HB);
    float*  score = (float*)(ws + WS_SCORE);

    hipLaunchKernelGGL(prep_kernel,  dim3(576),  dim3(256), 0, stream,
                       W, hidden, bias, Wbf, hb);
    hipLaunchKernelGGL(eproj_scores, dim3(1024), dim3(512), 0, stream,
                       enc, Wbf, hb, v, score);
    hipLaunchKernelGGL(softmax_kernel, dim3(32), dim3(256), 0, stream, score, out);
}